// Round 4
// baseline (600.102 us; speedup 1.0000x reference)
//
#include <hip/hip_runtime.h>
#include <stdint.h>

typedef __attribute__((ext_vector_type(8))) short short8;
typedef __attribute__((ext_vector_type(4))) float floatx4;

// ---------- helpers ----------
__device__ __forceinline__ unsigned short f2b(float f) {
    union { float f; uint32_t u; } v; v.f = f;
    uint32_t u = v.u;
    return (unsigned short)((u + 0x7FFFu + ((u >> 16) & 1u)) >> 16);  // RNE
}

// pack two fp32 -> two bf16 (round-half-up; bias negligible at threshold)
__device__ __forceinline__ uint32_t pk2(float a, float b) {
    union { float f; uint32_t u; } x, y; x.f = a; y.f = b;
    uint32_t ua = x.u + 0x8000u, ub = y.u + 0x8000u;
    return (ua >> 16) | (ub & 0xFFFF0000u);
}

__device__ __forceinline__ void async16(const void* g, void* l) {
    __builtin_amdgcn_global_load_lds(
        (const __attribute__((address_space(1))) void*)g,
        (__attribute__((address_space(3))) void*)l, 16, 0, 0);
}

// ---------- kernel 1: L2-normalize rows, emit bf16 ----------
__global__ void norm_kernel(const float* __restrict__ in,
                            unsigned short* __restrict__ xb, int D) {
    int b = blockIdx.x, t = threadIdx.x;
    const float* row = in + (size_t)b * D;
    float ss = 0.f;
    for (int i = t * 4; i < D; i += 1024) {
        float4 v = *(const float4*)(row + i);
        ss += v.x * v.x + v.y * v.y + v.z * v.z + v.w * v.w;
    }
    for (int off = 32; off > 0; off >>= 1) ss += __shfl_down(ss, off);
    __shared__ float wsum[4];
    __shared__ float rn_sh;
    if ((t & 63) == 0) wsum[t >> 6] = ss;
    __syncthreads();
    if (t == 0) rn_sh = rsqrtf(wsum[0] + wsum[1] + wsum[2] + wsum[3]);
    __syncthreads();
    float rn = rn_sh;
    unsigned short* orow = xb + (size_t)b * D;
    for (int i = t * 4; i < D; i += 1024) {
        float4 v = *(const float4*)(row + i);
        ushort4 o;
        o.x = f2b(v.x * rn); o.y = f2b(v.y * rn);
        o.z = f2b(v.z * rn); o.w = f2b(v.w * rn);
        *(ushort4*)(orow + i) = o;
    }
}

// ---------- kernel 2: fused GEMM, B streamed through registers ----------
// BM=256 (full batch, B read exactly once from HBM), BN=64, BK=64.
// Wave split 2x2: wave (wr,wc) owns rows wr*128..+128, cols wc*32..+32.
// B is loaded PER WAVE directly into the MFMA B-fragment lane layout
// (lane l <- B[tj*16+(l&15)][(l>>4)*8+..]) and packed to bf16 in-reg:
// no LDS round-trip, no lgkm dance.  A (L2-resident xb) is shared via
// double-buffered direct-to-LDS (64 KB).  Every iteration issues exactly
// 16 VMEM/wave (8 A-stage + 8 B-float4) one tile ahead; s_waitcnt
// vmcnt(16) completes exactly the PREVIOUS tile's 16 while the current
// 16 stay in flight across both barriers and the MFMA phase (per-wave
// count is exact because B is per-wave).  Tail: always-issue with
// clamped kt (redundant loads land in the dead buffer / dead regs).
// LDS swizzle unchanged: chunk c of row r at slot c^(r&7) (0 conflicts).
#define BKk 64
__global__ __launch_bounds__(256, 2)
void gemm_kernel(const unsigned short* __restrict__ xb,
                 const float* __restrict__ featB,
                 const float* __restrict__ centB,
                 const int* __restrict__ targets,
                 float* __restrict__ S, float* __restrict__ pos,
                 float* __restrict__ km,
                 int D, int K, int nbF) {
    __shared__ __align__(16) unsigned short Alds[2][256 * BKk];  // 64 KB

    const int t = threadIdx.x;
    const int w = t >> 6, l = t & 63;
    const int wr = w >> 1, wc = w & 1;                // 2x2 wave grid
    const bool isFeat = ((int)blockIdx.x < nbF);
    const int n0 = (isFeat ? (int)blockIdx.x : ((int)blockIdx.x - nbF)) * 64;
    const float* Bsrc = isFeat ? featB : centB;

    floatx4 acc[8][2];
#pragma unroll
    for (int ti = 0; ti < 8; ++ti)
#pragma unroll
        for (int tj = 0; tj < 2; ++tj)
            acc[ti][tj] = (floatx4){0.f, 0.f, 0.f, 0.f};

    const int kIters = D / BKk;                       // 32 (even)
    const char* xbB = (const char*)xb;
    // per-lane B base: row = n0 + wc*32 + (l&15), k-chunk = (l>>4)*8 floats
    const float* bgw = Bsrc + (size_t)(n0 + wc * 32 + (l & 15)) * D
                            + ((l >> 4) * 8);

    // 8 direct-to-LDS A loads for tile ktn into buffer nb (8 VMEM/wave)
    auto stageA = [&](int nb, int ktn) {
#pragma unroll
        for (int j = 0; j < 8; ++j) {
            int slin = j * 256 + t;                   // 16 B slot index
            int r = slin >> 3;                        // A row (0..255)
            int cg = (slin & 7) ^ (r & 7);            // global chunk for slot
            async16(xbB + (size_t)r * (D * 2) + (size_t)ktn * (BKk * 2) + cg * 16,
                    (char*)(&Alds[nb][0]) + slin * 16);
        }
    };
    // 8 float4 B loads for tile ktn into F (8 VMEM/wave), frag layout
    auto loadB = [&](float4 (&F)[2][2][2], int ktn) {
#pragma unroll
        for (int tj = 0; tj < 2; ++tj)
#pragma unroll
            for (int s = 0; s < 2; ++s)
#pragma unroll
                for (int q = 0; q < 2; ++q)
                    F[tj][s][q] = *(const float4*)(bgw + (size_t)tj * 16 * D
                                                   + ktn * BKk + s * 32 + q * 4);
    };
    // one K-step: 2 substeps of K=32; aF from LDS, bF packed from F regs
    auto compute = [&](int cb, const float4 (&F)[2][2][2]) {
        const char* Ab = (const char*)(&Alds[cb][0]);
#pragma unroll
        for (int s = 0; s < 2; ++s) {
            short8 aF[8], bF[2];
#pragma unroll
            for (int ti = 0; ti < 8; ++ti) {
                int R = wr * 128 + ti * 16 + (l & 15);
                int g = s * 4 + (l >> 4);
                aF[ti] = *(const short8*)(Ab + R * 128 + ((g ^ (R & 7)) * 16));
            }
#pragma unroll
            for (int tj = 0; tj < 2; ++tj) {
                uint32_t u0 = pk2(F[tj][s][0].x, F[tj][s][0].y);
                uint32_t u1 = pk2(F[tj][s][0].z, F[tj][s][0].w);
                uint32_t u2 = pk2(F[tj][s][1].x, F[tj][s][1].y);
                uint32_t u3 = pk2(F[tj][s][1].z, F[tj][s][1].w);
                union { uint32_t u[4]; short8 v; } cvt;
                cvt.u[0] = u0; cvt.u[1] = u1; cvt.u[2] = u2; cvt.u[3] = u3;
                bF[tj] = cvt.v;
            }
#pragma unroll
            for (int ti = 0; ti < 8; ++ti)
#pragma unroll
                for (int tj = 0; tj < 2; ++tj)
                    acc[ti][tj] = __builtin_amdgcn_mfma_f32_16x16x32_bf16(
                        aF[ti], bF[tj], acc[ti][tj], 0, 0, 0);
        }
    };

    float4 Bf[2][2][2], Bg[2][2][2];   // 2-deep B prefetch (static-indexed)

    // ---- prologue: tile 0 in flight (16 VMEM)
    stageA(0, 0);
    loadB(Bf, 0);

    // ---- main loop, unrolled x2 so buffers/regs are statically indexed
    for (int kt = 0; kt < kIters; kt += 2) {
        {   // even step: compute (buf0, Bf); prefetch kt+1 -> (buf1, Bg)
            int ktn = kt + 1 < kIters ? kt + 1 : kIters - 1;
            stageA(1, ktn);
            loadB(Bg, ktn);
            asm volatile("s_waitcnt vmcnt(16)" ::: "memory");
            __builtin_amdgcn_s_barrier();     // all waves' A(kt) landed
            asm volatile("" ::: "memory");
            compute(0, Bf);
            asm volatile("" ::: "memory");
            __builtin_amdgcn_s_barrier();     // buf0 reads done
        }
        {   // odd step: compute (buf1, Bg); prefetch kt+2 -> (buf0, Bf)
            int ktn = kt + 2 < kIters ? kt + 2 : kIters - 1;
            stageA(0, ktn);
            loadB(Bf, ktn);
            asm volatile("s_waitcnt vmcnt(16)" ::: "memory");
            __builtin_amdgcn_s_barrier();     // all waves' A(kt+1) landed
            asm volatile("" ::: "memory");
            compute(1, Bg);
            asm volatile("" ::: "memory");
            __builtin_amdgcn_s_barrier();     // buf1 reads done
        }
    }

    // epilogue.  C/D layout: col = l&15, row = (l>>4)*4 + reg  [m89-verified]
    if (isFeat) {
#pragma unroll
        for (int ti = 0; ti < 8; ++ti) {
#pragma unroll
            for (int r = 0; r < 4; ++r) {
                int row = wr * 128 + ti * 16 + ((l >> 4) << 2) + r;
                int tr = targets[row];
                int col0 = n0 + wc * 32 + (l & 15);
                float e = 0.f;
#pragma unroll
                for (int tj = 0; tj < 2; ++tj) {
                    float c = acc[ti][tj][r];
                    e += __expf(c * 20.0f);            // |c|<=~1 -> safe
                    if (tr == col0 + tj * 16) pos[row] = c;
                }
                e += __shfl_xor(e, 1); e += __shfl_xor(e, 2);
                e += __shfl_xor(e, 4); e += __shfl_xor(e, 8);
                if ((l & 15) == 0) atomicAdd(&S[row], e);
            }
        }
    } else {
#pragma unroll
        for (int ti = 0; ti < 8; ++ti) {
#pragma unroll
            for (int r = 0; r < 4; ++r) {
                int row = wr * 128 + ti * 16 + ((l >> 4) << 2) + r;
                size_t base = (size_t)row * K + n0 + wc * 32 + (l & 15);
#pragma unroll
                for (int tj = 0; tj < 2; ++tj)
                    km[base + tj * 16] = acc[ti][tj][r];
            }
        }
    }
}

// ---------- kernel 3: per-row top-neg_size (register-resident selection) ----
// Thread t owns elements k*256+t (k=0..31) in registers.  Per extraction:
// shuffle-reduce block argmax, owner lane clears + rescans locally.
__global__ __launch_bounds__(256, 4)
void topk_kernel(const float* __restrict__ kmr,
                 const int* __restrict__ pids,
                 const int* __restrict__ idxs,
                 const int* __restrict__ negsz,
                 float* __restrict__ topv, int K) {
    int b = blockIdx.x, t = threadIdx.x;
    int w = t >> 6, l = t & 63;
    const float* row = kmr + (size_t)b * K;
    float v[32];
#pragma unroll
    for (int k = 0; k < 32; ++k) v[k] = row[k * 256 + t];
    int gi = pids[idxs[b]];          // masked position (never top-20 in ref)
    if ((gi & 255) == t) {
        int kk = gi >> 8;
#pragma unroll
        for (int k = 0; k < 32; ++k) if (k == kk) v[k] = -1e30f;
    }
    float bv = v[0]; int bk = 0;
#pragma unroll
    for (int k = 1; k < 32; ++k) if (v[k] > bv) { bv = v[k]; bk = k; }

    __shared__ float rv[4];
    __shared__ int rg[4];
    int ns = *negsz; if (ns > 32) ns = 32;
    for (int j = 0; j < ns; ++j) {
        float mv = bv; int mg = bk * 256 + t;
#pragma unroll
        for (int off = 1; off < 64; off <<= 1) {
            float ov = __shfl_xor(mv, off);
            int og = __shfl_xor(mg, off);
            if (ov > mv) { mv = ov; mg = og; }
        }
        if (l == 0) { rv[w] = mv; rg[w] = mg; }
        __syncthreads();
        float gv = rv[0]; int gg = rg[0];
#pragma unroll
        for (int ww = 1; ww < 4; ++ww)
            if (rv[ww] > gv) { gv = rv[ww]; gg = rg[ww]; }
        if (t == 0) topv[b * 32 + j] = gv;
        if ((gg & 255) == t) {
            int kk = gg >> 8;
#pragma unroll
            for (int k = 0; k < 32; ++k) if (k == kk) v[k] = -1e30f;
            bv = v[0]; bk = 0;
#pragma unroll
            for (int k = 1; k < 32; ++k) if (v[k] > bv) { bv = v[k]; bk = k; }
        }
        __syncthreads();
    }
}

// ---------- kernel 4: confidence mask + losses + final scalar ----------
__global__ void final_kernel(const float* __restrict__ S,
                             const float* __restrict__ pos,
                             const float* __restrict__ topv,
                             const int* __restrict__ pids,
                             const int* __restrict__ idxs,
                             const int* __restrict__ negsz,
                             float* __restrict__ out, int B) {
    __shared__ int pid_sh[256];
    __shared__ int mode_sh[16];
    __shared__ float red[256];
    int t = threadIdx.x;
    if (t < B) pid_sh[t] = pids[idxs[t]];
    __syncthreads();
    int half = B >> 1;
    int G = half / 16;
    if (t < G) {
        int bestPid = 0x7FFFFFFF, bestCnt = -1;
        for (int i = 0; i < 16; ++i) {
            int p = pid_sh[t * 16 + i];
            int c = 0;
            for (int j = 0; j < 16; ++j) c += (pid_sh[t * 16 + j] == p) ? 1 : 0;
            if (c > bestCnt || (c == bestCnt && p < bestPid)) { bestCnt = c; bestPid = p; }
        }
        mode_sh[t] = bestPid;  // ties -> smallest id == bincount().argmax()
    }
    __syncthreads();
    float contrib = 0.f;
    if (t < B) {
        int hb = (t < half) ? t : t - half;
        float mask = (pid_sh[hb] == mode_sh[hb / 16]) ? 1.f : 0.f;
        int ns = *negsz; if (ns > 32) ns = 32;
        float p20 = pos[t] * 20.0f;
        float m = p20;
        for (int j = 0; j < ns; ++j) m = fmaxf(m, topv[t * 32 + j] * 20.0f);
        float se = __expf(p20 - m);
        for (int j = 0; j < ns; ++j) se += __expf(topv[t * 32 + j] * 20.0f - m);
        float ce_neg = m + logf(se) - p20;
        float ce_main = logf(S[t]) - p20;
        contrib = (0.2f * mask * ce_neg + ce_main) / (float)B;
    }
    red[t] = contrib;
    __syncthreads();
    for (int s = 128; s > 0; s >>= 1) {
        if (t < s) red[t] += red[t + s];
        __syncthreads();
    }
    if (t == 0) out[0] = red[0];
}

// ---------- launcher ----------
extern "C" void kernel_launch(void* const* d_in, const int* in_sizes, int n_in,
                              void* d_out, int out_size, void* d_ws, size_t ws_size,
                              hipStream_t stream) {
    const float* inputs   = (const float*)d_in[0];
    const float* features = (const float*)d_in[1];
    const float* cents    = (const float*)d_in[2];
    const int*   targets  = (const int*)d_in[3];
    const int*   pids     = (const int*)d_in[4];
    const int*   idxs     = (const int*)d_in[5];
    const int*   negsz    = (const int*)d_in[6];
    float* out = (float*)d_out;

    int Bb = in_sizes[3];            // 256
    int Dd = in_sizes[0] / Bb;       // 2048
    int Nn = in_sizes[1] / Dd;       // 32768
    int Kk = in_sizes[2] / Dd;       // 8192

    char* ws = (char*)d_ws;
    unsigned short* xb = (unsigned short*)ws;
    size_t o = (size_t)Bb * Dd * 2;
    float* km   = (float*)(ws + o); o += (size_t)Bb * Kk * 4;
    float* S    = (float*)(ws + o); o += (size_t)Bb * 4;
    float* pos  = (float*)(ws + o); o += (size_t)Bb * 4;
    float* topv = (float*)(ws + o); o += (size_t)Bb * 32 * 4;

    hipMemsetAsync(S, 0, (size_t)Bb * 4, stream);
    norm_kernel<<<Bb, 256, 0, stream>>>(inputs, xb, Dd);
    int nbF = Nn / 64, nbC = Kk / 64;
    gemm_kernel<<<nbF + nbC, 256, 0, stream>>>(xb, features, cents, targets,
                                               S, pos, km, Dd, Kk, nbF);
    topk_kernel<<<Bb, 256, 0, stream>>>(km, pids, idxs, negsz, topv, Kk);
    final_kernel<<<1, 256, 0, stream>>>(S, pos, topv, pids, idxs, negsz, out, Bb);
}

// Round 5
// 583.689 us; speedup vs baseline: 1.0281x; 1.0281x over previous
//
#include <hip/hip_runtime.h>
#include <stdint.h>

typedef __attribute__((ext_vector_type(8))) short short8;
typedef __attribute__((ext_vector_type(4))) float floatx4;

// ---------- helpers ----------
__device__ __forceinline__ unsigned short f2b(float f) {
    union { float f; uint32_t u; } v; v.f = f;
    uint32_t u = v.u;
    return (unsigned short)((u + 0x7FFFu + ((u >> 16) & 1u)) >> 16);  // RNE
}

// pack two fp32 -> two bf16 (round-half-up; bias negligible at threshold)
__device__ __forceinline__ uint32_t pk2(float a, float b) {
    union { float f; uint32_t u; } x, y; x.f = a; y.f = b;
    uint32_t ua = x.u + 0x8000u, ub = y.u + 0x8000u;
    return (ua >> 16) | (ub & 0xFFFF0000u);
}

__device__ __forceinline__ void async16(const void* g, void* l) {
    __builtin_amdgcn_global_load_lds(
        (const __attribute__((address_space(1))) void*)g,
        (__attribute__((address_space(3))) void*)l, 16, 0, 0);
}

// ---------- kernel 1: L2-normalize rows, emit bf16 ----------
__global__ void norm_kernel(const float* __restrict__ in,
                            unsigned short* __restrict__ xb, int D) {
    int b = blockIdx.x, t = threadIdx.x;
    const float* row = in + (size_t)b * D;
    float ss = 0.f;
    for (int i = t * 4; i < D; i += 1024) {
        float4 v = *(const float4*)(row + i);
        ss += v.x * v.x + v.y * v.y + v.z * v.z + v.w * v.w;
    }
    for (int off = 32; off > 0; off >>= 1) ss += __shfl_down(ss, off);
    __shared__ float wsum[4];
    __shared__ float rn_sh;
    if ((t & 63) == 0) wsum[t >> 6] = ss;
    __syncthreads();
    if (t == 0) rn_sh = rsqrtf(wsum[0] + wsum[1] + wsum[2] + wsum[3]);
    __syncthreads();
    float rn = rn_sh;
    unsigned short* orow = xb + (size_t)b * D;
    for (int i = t * 4; i < D; i += 1024) {
        float4 v = *(const float4*)(row + i);
        ushort4 o;
        o.x = f2b(v.x * rn); o.y = f2b(v.y * rn);
        o.z = f2b(v.z * rn); o.w = f2b(v.w * rn);
        *(ushort4*)(orow + i) = o;
    }
}

// ---------- kernel 2: fused GEMM, 512-thread blocks ----------
// BM=256 (full batch, B read exactly once from HBM), BN=64, BK=64.
// r0-r4 post-mortem: r0's simple 2-barrier loop at 2 waves/SIMD runs
// ~5000 cy/K-step/CU vs ~2000 cy of accountable resources (latency-bound);
// r2 proved 4 waves/SIMD cuts per-step cost to ~3000 cy but paid 2x
// replicated A-staging (more blocks).  This version buys 4 waves/SIMD
// WITHOUT extra staging: 512 threads/block (8 waves, output split 4x2),
// same grid 640, same 40KB LDS, same proven 2-barrier structure.
// LDS rows are 128 B (=32 banks); 16 B chunk c of row r stored at slot
// c ^ (r&7)  ->  every b128 access phase is <=2-way (measured 0 conflicts).
#define BKk 64
__global__ __launch_bounds__(512, 4)
void gemm_kernel(const unsigned short* __restrict__ xb,
                 const float* __restrict__ featB,
                 const float* __restrict__ centB,
                 const int* __restrict__ targets,
                 float* __restrict__ S, float* __restrict__ pos,
                 float* __restrict__ km,
                 int D, int K, int nbF) {
    __shared__ __align__(16) unsigned short Alds[256 * BKk];  // 32 KB
    __shared__ __align__(16) unsigned short Blds[64 * BKk];   // 8 KB

    const int t = threadIdx.x;
    const int w = t >> 6, l = t & 63;
    const int wr = w >> 1, wc = w & 1;                // 4x2 wave grid
    const bool isFeat = ((int)blockIdx.x < nbF);
    const int n0 = (isFeat ? (int)blockIdx.x : ((int)blockIdx.x - nbF)) * 64;
    const float* Bsrc = isFeat ? featB : centB;

    floatx4 acc[4][2];
#pragma unroll
    for (int ti = 0; ti < 4; ++ti)
#pragma unroll
        for (int tj = 0; tj < 2; ++tj)
            acc[ti][tj] = (floatx4){0.f, 0.f, 0.f, 0.f};

    const int kIters = D / BKk;                       // 32
    // B staging: 64 rows x 64 cols fp32 -> bf16.  8 threads/row, each
    // thread loads 8 floats and writes ONE swizzled 16 B chunk.
    const int brow = t >> 3, bq = t & 7;
    const float* bg0 = Bsrc + (size_t)(n0 + brow) * D + bq * 8;
    const int bslot = (bq ^ (brow & 7)) * 16;         // swizzled chunk slot
    const char* xbB = (const char*)xb;

    for (int kt = 0; kt < kIters; ++kt) {
        // ---- stage A: 32 KB via direct-to-LDS; swizzle folded into src addr
#pragma unroll
        for (int j = 0; j < 4; ++j) {
            int slin = j * 512 + t;                   // 16 B slot index
            int r = slin >> 3;                        // A row (0..255)
            int cg = (slin & 7) ^ (r & 7);            // global chunk for slot
            async16(xbB + (size_t)r * (D * 2) + kt * (BKk * 2) + cg * 16,
                    (char*)Alds + slin * 16);
        }
        // ---- stage B: fp32 -> bf16, one swizzled ds_write_b128 per thread
        {
            const float* bg = bg0 + kt * BKk;
            float4 f0 = *(const float4*)(bg);
            float4 f1 = *(const float4*)(bg + 4);
            uint4 p;
            p.x = pk2(f0.x, f0.y); p.y = pk2(f0.z, f0.w);
            p.z = pk2(f1.x, f1.y); p.w = pk2(f1.z, f1.w);
            *(uint4*)((char*)Blds + brow * 128 + bslot) = p;
        }
        __syncthreads();

        // ---- compute: 2 sub-steps of K=32, 8 MFMA each per wave
#pragma unroll
        for (int s = 0; s < 2; ++s) {
            short8 aF[4], bF[2];
#pragma unroll
            for (int ti = 0; ti < 4; ++ti) {
                int R = wr * 64 + ti * 16 + (l & 15);
                int g = s * 4 + (l >> 4);
                aF[ti] = *(const short8*)((const char*)Alds +
                          R * 128 + ((g ^ (R & 7)) * 16));
            }
#pragma unroll
            for (int tj = 0; tj < 2; ++tj) {
                int Rn = wc * 32 + tj * 16 + (l & 15);
                int g = s * 4 + (l >> 4);
                bF[tj] = *(const short8*)((const char*)Blds +
                          Rn * 128 + ((g ^ (Rn & 7)) * 16));
            }
#pragma unroll
            for (int ti = 0; ti < 4; ++ti)
#pragma unroll
                for (int tj = 0; tj < 2; ++tj)
                    acc[ti][tj] = __builtin_amdgcn_mfma_f32_16x16x32_bf16(
                        aF[ti], bF[tj], acc[ti][tj], 0, 0, 0);
        }
        __syncthreads();
    }

    // epilogue.  C/D layout: col = l&15, row = (l>>4)*4 + reg  [m89-verified]
    if (isFeat) {
#pragma unroll
        for (int ti = 0; ti < 4; ++ti) {
#pragma unroll
            for (int r = 0; r < 4; ++r) {
                int row = wr * 64 + ti * 16 + ((l >> 4) << 2) + r;
                int tr = targets[row];
                int col0 = n0 + wc * 32 + (l & 15);
                float e = 0.f;
#pragma unroll
                for (int tj = 0; tj < 2; ++tj) {
                    float c = acc[ti][tj][r];
                    e += __expf(c * 20.0f);            // |c|<=~1 -> safe
                    if (tr == col0 + tj * 16) pos[row] = c;
                }
                // sum e across the 16 lanes sharing this row (xor 1,2,4,8
                // only permutes l&15; row depends only on l>>4)
                e += __shfl_xor(e, 1); e += __shfl_xor(e, 2);
                e += __shfl_xor(e, 4); e += __shfl_xor(e, 8);
                if ((l & 15) == 0) atomicAdd(&S[row], e);
            }
        }
    } else {
#pragma unroll
        for (int ti = 0; ti < 4; ++ti) {
#pragma unroll
            for (int r = 0; r < 4; ++r) {
                int row = wr * 64 + ti * 16 + ((l >> 4) << 2) + r;
                size_t base = (size_t)row * K + n0 + wc * 32 + (l & 15);
#pragma unroll
                for (int tj = 0; tj < 2; ++tj)
                    km[base + tj * 16] = acc[ti][tj][r];
            }
        }
    }
}

// ---------- kernel 3: per-row top-neg_size (register-resident selection) ----
// Thread t owns elements k*256+t (k=0..31) in registers.  Per extraction:
// shuffle-reduce block argmax, owner lane clears + rescans locally.
__global__ __launch_bounds__(256, 4)
void topk_kernel(const float* __restrict__ kmr,
                 const int* __restrict__ pids,
                 const int* __restrict__ idxs,
                 const int* __restrict__ negsz,
                 float* __restrict__ topv, int K) {
    int b = blockIdx.x, t = threadIdx.x;
    int w = t >> 6, l = t & 63;
    const float* row = kmr + (size_t)b * K;
    float v[32];
#pragma unroll
    for (int k = 0; k < 32; ++k) v[k] = row[k * 256 + t];
    int gi = pids[idxs[b]];          // masked position (never top-20 in ref)
    if ((gi & 255) == t) {
        int kk = gi >> 8;
#pragma unroll
        for (int k = 0; k < 32; ++k) if (k == kk) v[k] = -1e30f;
    }
    float bv = v[0]; int bk = 0;
#pragma unroll
    for (int k = 1; k < 32; ++k) if (v[k] > bv) { bv = v[k]; bk = k; }

    __shared__ float rv[4];
    __shared__ int rg[4];
    int ns = *negsz; if (ns > 32) ns = 32;
    for (int j = 0; j < ns; ++j) {
        float mv = bv; int mg = bk * 256 + t;
#pragma unroll
        for (int off = 1; off < 64; off <<= 1) {
            float ov = __shfl_xor(mv, off);
            int og = __shfl_xor(mg, off);
            if (ov > mv) { mv = ov; mg = og; }
        }
        if (l == 0) { rv[w] = mv; rg[w] = mg; }
        __syncthreads();
        float gv = rv[0]; int gg = rg[0];
#pragma unroll
        for (int ww = 1; ww < 4; ++ww)
            if (rv[ww] > gv) { gv = rv[ww]; gg = rg[ww]; }
        if (t == 0) topv[b * 32 + j] = gv;
        if ((gg & 255) == t) {
            int kk = gg >> 8;
#pragma unroll
            for (int k = 0; k < 32; ++k) if (k == kk) v[k] = -1e30f;
            bv = v[0]; bk = 0;
#pragma unroll
            for (int k = 1; k < 32; ++k) if (v[k] > bv) { bv = v[k]; bk = k; }
        }
        __syncthreads();
    }
}

// ---------- kernel 4: confidence mask + losses + final scalar ----------
__global__ void final_kernel(const float* __restrict__ S,
                             const float* __restrict__ pos,
                             const float* __restrict__ topv,
                             const int* __restrict__ pids,
                             const int* __restrict__ idxs,
                             const int* __restrict__ negsz,
                             float* __restrict__ out, int B) {
    __shared__ int pid_sh[256];
    __shared__ int mode_sh[16];
    __shared__ float red[256];
    int t = threadIdx.x;
    if (t < B) pid_sh[t] = pids[idxs[t]];
    __syncthreads();
    int half = B >> 1;
    int G = half / 16;
    if (t < G) {
        int bestPid = 0x7FFFFFFF, bestCnt = -1;
        for (int i = 0; i < 16; ++i) {
            int p = pid_sh[t * 16 + i];
            int c = 0;
            for (int j = 0; j < 16; ++j) c += (pid_sh[t * 16 + j] == p) ? 1 : 0;
            if (c > bestCnt || (c == bestCnt && p < bestPid)) { bestCnt = c; bestPid = p; }
        }
        mode_sh[t] = bestPid;  // ties -> smallest id == bincount().argmax()
    }
    __syncthreads();
    float contrib = 0.f;
    if (t < B) {
        int hb = (t < half) ? t : t - half;
        float mask = (pid_sh[hb] == mode_sh[hb / 16]) ? 1.f : 0.f;
        int ns = *negsz; if (ns > 32) ns = 32;
        float p20 = pos[t] * 20.0f;
        float m = p20;
        for (int j = 0; j < ns; ++j) m = fmaxf(m, topv[t * 32 + j] * 20.0f);
        float se = __expf(p20 - m);
        for (int j = 0; j < ns; ++j) se += __expf(topv[t * 32 + j] * 20.0f - m);
        float ce_neg = m + logf(se) - p20;
        float ce_main = logf(S[t]) - p20;
        contrib = (0.2f * mask * ce_neg + ce_main) / (float)B;
    }
    red[t] = contrib;
    __syncthreads();
    for (int s = 128; s > 0; s >>= 1) {
        if (t < s) red[t] += red[t + s];
        __syncthreads();
    }
    if (t == 0) out[0] = red[0];
}

// ---------- launcher ----------
extern "C" void kernel_launch(void* const* d_in, const int* in_sizes, int n_in,
                              void* d_out, int out_size, void* d_ws, size_t ws_size,
                              hipStream_t stream) {
    const float* inputs   = (const float*)d_in[0];
    const float* features = (const float*)d_in[1];
    const float* cents    = (const float*)d_in[2];
    const int*   targets  = (const int*)d_in[3];
    const int*   pids     = (const int*)d_in[4];
    const int*   idxs     = (const int*)d_in[5];
    const int*   negsz    = (const int*)d_in[6];
    float* out = (float*)d_out;

    int Bb = in_sizes[3];            // 256
    int Dd = in_sizes[0] / Bb;       // 2048
    int Nn = in_sizes[1] / Dd;       // 32768
    int Kk = in_sizes[2] / Dd;       // 8192

    char* ws = (char*)d_ws;
    unsigned short* xb = (unsigned short*)ws;
    size_t o = (size_t)Bb * Dd * 2;
    float* km   = (float*)(ws + o); o += (size_t)Bb * Kk * 4;
    float* S    = (float*)(ws + o); o += (size_t)Bb * 4;
    float* pos  = (float*)(ws + o); o += (size_t)Bb * 4;
    float* topv = (float*)(ws + o); o += (size_t)Bb * 32 * 4;

    hipMemsetAsync(S, 0, (size_t)Bb * 4, stream);
    norm_kernel<<<Bb, 256, 0, stream>>>(inputs, xb, Dd);
    int nbF = Nn / 64, nbC = Kk / 64;
    gemm_kernel<<<nbF + nbC, 512, 0, stream>>>(xb, features, cents, targets,
                                               S, pos, km, Dd, Kk, nbF);
    topk_kernel<<<Bb, 256, 0, stream>>>(km, pids, idxs, negsz, topv, Kk);
    final_kernel<<<1, 256, 0, stream>>>(S, pos, topv, pids, idxs, negsz, out, Bb);
}

// Round 6
// 538.651 us; speedup vs baseline: 1.1141x; 1.0836x over previous
//
#include <hip/hip_runtime.h>
#include <stdint.h>

typedef __attribute__((ext_vector_type(8))) short short8;
typedef __attribute__((ext_vector_type(4))) float floatx4;

// ---------- helpers ----------
__device__ __forceinline__ unsigned short f2b(float f) {
    union { float f; uint32_t u; } v; v.f = f;
    uint32_t u = v.u;
    return (unsigned short)((u + 0x7FFFu + ((u >> 16) & 1u)) >> 16);  // RNE
}

// pack two fp32 -> two bf16 (round-half-up; bias negligible at threshold)
__device__ __forceinline__ uint32_t pk2(float a, float b) {
    union { float f; uint32_t u; } x, y; x.f = a; y.f = b;
    uint32_t ua = x.u + 0x8000u, ub = y.u + 0x8000u;
    return (ua >> 16) | (ub & 0xFFFF0000u);
}

// ---------- kernel 1: L2-normalize rows, emit bf16 ----------
__global__ void norm_kernel(const float* __restrict__ in,
                            unsigned short* __restrict__ xb, int D) {
    int b = blockIdx.x, t = threadIdx.x;
    const float* row = in + (size_t)b * D;
    float ss = 0.f;
    for (int i = t * 4; i < D; i += 1024) {
        float4 v = *(const float4*)(row + i);
        ss += v.x * v.x + v.y * v.y + v.z * v.z + v.w * v.w;
    }
    for (int off = 32; off > 0; off >>= 1) ss += __shfl_down(ss, off);
    __shared__ float wsum[4];
    __shared__ float rn_sh;
    if ((t & 63) == 0) wsum[t >> 6] = ss;
    __syncthreads();
    if (t == 0) rn_sh = rsqrtf(wsum[0] + wsum[1] + wsum[2] + wsum[3]);
    __syncthreads();
    float rn = rn_sh;
    unsigned short* orow = xb + (size_t)b * D;
    for (int i = t * 4; i < D; i += 1024) {
        float4 v = *(const float4*)(row + i);
        ushort4 o;
        o.x = f2b(v.x * rn); o.y = f2b(v.y * rn);
        o.z = f2b(v.z * rn); o.w = f2b(v.w * rn);
        *(ushort4*)(orow + i) = o;
    }
}

// ---------- kernel 2: fused GEMM, A direct-from-L2, BK=256 ----------
// r0-r5 post-mortem: 64 barrier-pairs/block with ~800cy compute between
// them kept the per-block K-step at ~12,600cy (latency/drain-bound, all
// pipes <11%).  Also: the old A-LDS staging was SHARED-NOTHING (wave w
// only read the rows it staged) -> pure overhead for an L2-resident xb.
// This version:
//  - A fragments read DIRECTLY global->VGPR (per instr: 16 rows x 64 B,
//    fully-consumed cache lines; xb = 1 MB, L2-resident, reused 640x).
//  - LDS holds only B (64 rows x 256 bf16 = 32 KB, single buffer).
//  - BK=256: 8 K-steps, 16 barriers total (4x fewer), B rows read in
//    1 KB contiguous runs (4x better DRAM burst locality).
//  - compute phase per barrier-pair is 128 MFMA/wave + A-loads with NO
//    internal barriers -> compiler free to software-pipeline.
// LDS B swizzle: row stride 512 B = 32 chunks of 16 B; chunk c stored at
// slot c ^ (row&7): every 16-lane read phase is <=2-way (free, m136).
#define BKk 256
__global__ __launch_bounds__(256, 3)
void gemm_kernel(const unsigned short* __restrict__ xb,
                 const float* __restrict__ featB,
                 const float* __restrict__ centB,
                 const int* __restrict__ targets,
                 float* __restrict__ S, float* __restrict__ pos,
                 float* __restrict__ km,
                 int D, int K, int nbF) {
    __shared__ __align__(16) unsigned short Blds[64 * BKk];   // 32 KB

    const int t = threadIdx.x;
    const int w = t >> 6, l = t & 63;
    const int lo = l & 15, hi = l >> 4;
    const bool isFeat = ((int)blockIdx.x < nbF);
    const int n0 = (isFeat ? (int)blockIdx.x : ((int)blockIdx.x - nbF)) * 64;
    const float* Bsrc = isFeat ? featB : centB;

    floatx4 acc[4][4];
#pragma unroll
    for (int ti = 0; ti < 4; ++ti)
#pragma unroll
        for (int tj = 0; tj < 4; ++tj)
            acc[ti][tj] = (floatx4){0.f, 0.f, 0.f, 0.f};

    const int kIters = D / BKk;                       // 8
    const char* xbB = (const char*)xb;

    // B staging map: bf16 chunk index c = j*256 + t (j=0..7, 2048 chunks =
    // 64 rows x 32 chunks).  row = j*8 + (t>>5), cc = t&31 (constant).
    // Global src: 32 B fp32 at (n0+row)*D + kt*256 + cc*8.  Lanes 0-31 of a
    // wave cover one full 1 KB row-run (fa/fb halves merge in L1).
    const int bcc   = t & 31;
    const int brow0 = t >> 5;
    const int bslot = (bcc ^ (brow0 & 7)) * 16;       // row&7 == brow0&7
    const float* bgbase = Bsrc + (size_t)(n0 + brow0) * D + bcc * 8;

    for (int kt = 0; kt < kIters; ++kt) {
        // ---- stage B: 64 KB fp32 -> 32 KB bf16 LDS, swizzled
#pragma unroll
        for (int j = 0; j < 8; ++j) {
            const float* src = bgbase + (size_t)j * 8 * D + kt * BKk;
            float4 fa = *(const float4*)(src);
            float4 fb = *(const float4*)(src + 4);
            uint4 p;
            p.x = pk2(fa.x, fa.y); p.y = pk2(fa.z, fa.w);
            p.z = pk2(fb.x, fb.y); p.w = pk2(fb.z, fb.w);
            *(uint4*)((char*)Blds + (j * 8 + brow0) * 512 + bslot) = p;
        }
        __syncthreads();

        // ---- compute: 8 sub-steps of K=32; A straight from global (L2)
#pragma unroll
        for (int kk = 0; kk < 8; ++kk) {
            short8 aF[4], bF[4];
#pragma unroll
            for (int ti = 0; ti < 4; ++ti) {
                int R = w * 64 + ti * 16 + lo;
                aF[ti] = *(const short8*)(xbB + (size_t)R * (D * 2)
                          + kt * (BKk * 2) + kk * 64 + hi * 16);
            }
#pragma unroll
            for (int tj = 0; tj < 4; ++tj) {
                int Rn = tj * 16 + lo;
                int chunk = kk * 4 + hi;
                bF[tj] = *(const short8*)((const char*)Blds +
                          Rn * 512 + ((chunk ^ (Rn & 7)) * 16));
            }
#pragma unroll
            for (int ti = 0; ti < 4; ++ti)
#pragma unroll
                for (int tj = 0; tj < 4; ++tj)
                    acc[ti][tj] = __builtin_amdgcn_mfma_f32_16x16x32_bf16(
                        aF[ti], bF[tj], acc[ti][tj], 0, 0, 0);
        }
        __syncthreads();   // B-LDS reads done before next stage overwrites
    }

    // epilogue.  C/D layout: col = l&15, row = (l>>4)*4 + reg  [m89-verified]
    if (isFeat) {
#pragma unroll
        for (int ti = 0; ti < 4; ++ti) {
#pragma unroll
            for (int r = 0; r < 4; ++r) {
                int row = w * 64 + ti * 16 + ((l >> 4) << 2) + r;
                int tr = targets[row];
                int col0 = n0 + (l & 15);
                float e = 0.f;
#pragma unroll
                for (int tj = 0; tj < 4; ++tj) {
                    float c = acc[ti][tj][r];
                    e += __expf(c * 20.0f);            // |c|<=~1 -> safe
                    if (tr == col0 + tj * 16) pos[row] = c;
                }
                e += __shfl_xor(e, 1); e += __shfl_xor(e, 2);
                e += __shfl_xor(e, 4); e += __shfl_xor(e, 8);
                if ((l & 15) == 0) atomicAdd(&S[row], e);
            }
        }
    } else {
#pragma unroll
        for (int ti = 0; ti < 4; ++ti) {
#pragma unroll
            for (int r = 0; r < 4; ++r) {
                int row = w * 64 + ti * 16 + ((l >> 4) << 2) + r;
                size_t base = (size_t)row * K + n0 + (l & 15);
#pragma unroll
                for (int tj = 0; tj < 4; ++tj)
                    km[base + tj * 16] = acc[ti][tj][r];
            }
        }
    }
}

// ---------- kernel 3: per-row top-neg_size (register-resident selection) ----
// Thread t owns elements k*256+t (k=0..31) in registers.  Per extraction:
// shuffle-reduce block argmax, owner lane clears + rescans locally.
__global__ __launch_bounds__(256, 4)
void topk_kernel(const float* __restrict__ kmr,
                 const int* __restrict__ pids,
                 const int* __restrict__ idxs,
                 const int* __restrict__ negsz,
                 float* __restrict__ topv, int K) {
    int b = blockIdx.x, t = threadIdx.x;
    int w = t >> 6, l = t & 63;
    const float* row = kmr + (size_t)b * K;
    float v[32];
#pragma unroll
    for (int k = 0; k < 32; ++k) v[k] = row[k * 256 + t];
    int gi = pids[idxs[b]];          // masked position (never top-20 in ref)
    if ((gi & 255) == t) {
        int kk = gi >> 8;
#pragma unroll
        for (int k = 0; k < 32; ++k) if (k == kk) v[k] = -1e30f;
    }
    float bv = v[0]; int bk = 0;
#pragma unroll
    for (int k = 1; k < 32; ++k) if (v[k] > bv) { bv = v[k]; bk = k; }

    __shared__ float rv[4];
    __shared__ int rg[4];
    int ns = *negsz; if (ns > 32) ns = 32;
    for (int j = 0; j < ns; ++j) {
        float mv = bv; int mg = bk * 256 + t;
#pragma unroll
        for (int off = 1; off < 64; off <<= 1) {
            float ov = __shfl_xor(mv, off);
            int og = __shfl_xor(mg, off);
            if (ov > mv) { mv = ov; mg = og; }
        }
        if (l == 0) { rv[w] = mv; rg[w] = mg; }
        __syncthreads();
        float gv = rv[0]; int gg = rg[0];
#pragma unroll
        for (int ww = 1; ww < 4; ++ww)
            if (rv[ww] > gv) { gv = rv[ww]; gg = rg[ww]; }
        if (t == 0) topv[b * 32 + j] = gv;
        if ((gg & 255) == t) {
            int kk = gg >> 8;
#pragma unroll
            for (int k = 0; k < 32; ++k) if (k == kk) v[k] = -1e30f;
            bv = v[0]; bk = 0;
#pragma unroll
            for (int k = 1; k < 32; ++k) if (v[k] > bv) { bv = v[k]; bk = k; }
        }
        __syncthreads();
    }
}

// ---------- kernel 4: confidence mask + losses + final scalar ----------
__global__ void final_kernel(const float* __restrict__ S,
                             const float* __restrict__ pos,
                             const float* __restrict__ topv,
                             const int* __restrict__ pids,
                             const int* __restrict__ idxs,
                             const int* __restrict__ negsz,
                             float* __restrict__ out, int B) {
    __shared__ int pid_sh[256];
    __shared__ int mode_sh[16];
    __shared__ float red[256];
    int t = threadIdx.x;
    if (t < B) pid_sh[t] = pids[idxs[t]];
    __syncthreads();
    int half = B >> 1;
    int G = half / 16;
    if (t < G) {
        int bestPid = 0x7FFFFFFF, bestCnt = -1;
        for (int i = 0; i < 16; ++i) {
            int p = pid_sh[t * 16 + i];
            int c = 0;
            for (int j = 0; j < 16; ++j) c += (pid_sh[t * 16 + j] == p) ? 1 : 0;
            if (c > bestCnt || (c == bestCnt && p < bestPid)) { bestCnt = c; bestPid = p; }
        }
        mode_sh[t] = bestPid;  // ties -> smallest id == bincount().argmax()
    }
    __syncthreads();
    float contrib = 0.f;
    if (t < B) {
        int hb = (t < half) ? t : t - half;
        float mask = (pid_sh[hb] == mode_sh[hb / 16]) ? 1.f : 0.f;
        int ns = *negsz; if (ns > 32) ns = 32;
        float p20 = pos[t] * 20.0f;
        float m = p20;
        for (int j = 0; j < ns; ++j) m = fmaxf(m, topv[t * 32 + j] * 20.0f);
        float se = __expf(p20 - m);
        for (int j = 0; j < ns; ++j) se += __expf(topv[t * 32 + j] * 20.0f - m);
        float ce_neg = m + logf(se) - p20;
        float ce_main = logf(S[t]) - p20;
        contrib = (0.2f * mask * ce_neg + ce_main) / (float)B;
    }
    red[t] = contrib;
    __syncthreads();
    for (int s = 128; s > 0; s >>= 1) {
        if (t < s) red[t] += red[t + s];
        __syncthreads();
    }
    if (t == 0) out[0] = red[0];
}

// ---------- launcher ----------
extern "C" void kernel_launch(void* const* d_in, const int* in_sizes, int n_in,
                              void* d_out, int out_size, void* d_ws, size_t ws_size,
                              hipStream_t stream) {
    const float* inputs   = (const float*)d_in[0];
    const float* features = (const float*)d_in[1];
    const float* cents    = (const float*)d_in[2];
    const int*   targets  = (const int*)d_in[3];
    const int*   pids     = (const int*)d_in[4];
    const int*   idxs     = (const int*)d_in[5];
    const int*   negsz    = (const int*)d_in[6];
    float* out = (float*)d_out;

    int Bb = in_sizes[3];            // 256
    int Dd = in_sizes[0] / Bb;       // 2048
    int Nn = in_sizes[1] / Dd;       // 32768
    int Kk = in_sizes[2] / Dd;       // 8192

    char* ws = (char*)d_ws;
    unsigned short* xb = (unsigned short*)ws;
    size_t o = (size_t)Bb * Dd * 2;
    float* km   = (float*)(ws + o); o += (size_t)Bb * Kk * 4;
    float* S    = (float*)(ws + o); o += (size_t)Bb * 4;
    float* pos  = (float*)(ws + o); o += (size_t)Bb * 4;
    float* topv = (float*)(ws + o); o += (size_t)Bb * 32 * 4;

    hipMemsetAsync(S, 0, (size_t)Bb * 4, stream);
    norm_kernel<<<Bb, 256, 0, stream>>>(inputs, xb, Dd);
    int nbF = Nn / 64, nbC = Kk / 64;
    gemm_kernel<<<nbF + nbC, 256, 0, stream>>>(xb, features, cents, targets,
                                               S, pos, km, Dd, Kk, nbF);
    topk_kernel<<<Bb, 256, 0, stream>>>(km, pids, idxs, negsz, topv, Kk);
    final_kernel<<<1, 256, 0, stream>>>(S, pos, topv, pids, idxs, negsz, out, Bb);
}